// Round 5
// baseline (322.615 us; speedup 1.0000x reference)
//
#include <hip/hip_runtime.h>
#include <stdint.h>

// x: (32, 256, 58, 58) f32 binary {0,1};  w: (256, 256, 3, 3) f32
// out: (32, 256, 56, 56) f32 = alpha[o]*(2S - 2304), S = XNOR matches
// out = fma(-2*alpha[o], P, 2304*alpha[o]),  P = popcount(xbits ^ wbits)

#define BATCH 32
#define C_IN 256
#define OCH 256
#define HIN 58
#define WIN2 58
#define HOUT 56
#define WOUT 56
#define TAPS 9
#define WWORDS 8            // 256 channels / 32 bits
#define HWIN (HIN * WIN2)   // 3364
#define HWOUT (HOUT * WOUT) // 3136
#define NPOS (BATCH * HWIN) // 107648
#define OGRP 8              // o-channels per thread (32 y-groups)
#define POSP 4              // output positions per thread (register reuse of weights)

// ---------------------------------------------------------------------------
// Kernel 1: bit-pack x along channels. Thread ↔ (word w, 2 consecutive pos).
// ---------------------------------------------------------------------------
__global__ __launch_bounds__(256) void pack_x_kernel(
    const float* __restrict__ x, uint32_t* __restrict__ xp)
{
    int t = blockIdx.x * 256 + threadIdx.x;
    int w = t / (NPOS / 2);
    int q = t - w * (NPOS / 2);
    int p = 2 * q;
    int b = p / HWIN;
    int r = p - b * HWIN;
    const float* xb = x + ((size_t)(b * C_IN + w * 32)) * HWIN + r;
    uint32_t m0 = 0u, m1 = 0u;
    #pragma unroll
    for (int j = 0; j < 32; ++j) {
        float2 v = *(const float2*)(xb + (size_t)j * HWIN);
        m0 |= (v.x > 0.5f ? 1u : 0u) << j;
        m1 |= (v.y > 0.5f ? 1u : 0u) << j;
    }
    xp[(size_t)p * WWORDS + w] = m0;
    xp[(size_t)(p + 1) * WWORDS + w] = m1;
}

// ---------------------------------------------------------------------------
// Kernel 2: pack weights TAP-MAJOR (wq[tap][o][8]) + per-o scale/bias.
// ---------------------------------------------------------------------------
__global__ __launch_bounds__(256) void pack_w_kernel(
    const float* __restrict__ wt, uint32_t* __restrict__ wq,
    float* __restrict__ sA, float* __restrict__ sB)
{
    int o = blockIdx.x;
    int c = threadIdx.x;
    const float* wb = wt + ((size_t)o * C_IN + c) * TAPS;
    float wv[TAPS];
    float s = 0.f;
    #pragma unroll
    for (int t = 0; t < TAPS; ++t) {
        wv[t] = wb[t];
        s += fabsf(wv[t]);
    }
    int wave = c >> 6, lane = c & 63;
    #pragma unroll
    for (int t = 0; t < TAPS; ++t) {
        unsigned long long m = __ballot(wv[t] >= 0.0f);
        if (lane == 0) {
            wq[((size_t)t * OCH + o) * WWORDS + wave * 2]     = (uint32_t)m;
            wq[((size_t)t * OCH + o) * WWORDS + wave * 2 + 1] = (uint32_t)(m >> 32);
        }
    }
    __shared__ float red[256];
    red[c] = s;
    __syncthreads();
    for (int off = 128; off > 0; off >>= 1) {
        if (c < off) red[c] += red[c + off];
        __syncthreads();
    }
    if (c == 0) {
        float alpha = red[0] / (float)(C_IN * HWIN);   // n = C*H*W per reference
        sA[o] = -2.0f * alpha;
        sB[o] = (float)(C_IN * TAPS) * alpha;          // 2304 * alpha
    }
}

// ---------------------------------------------------------------------------
// Kernel 3: main. Thread ↔ 4 output positions x 8 o-channels.
// Register reuse: each weight uint4 pulled from LDS is applied to 4 x-windows
// held in VGPRs -> 4x fewer ds_read_b128/wave than R4 (576 -> 144); the
// per-CU LDS pipe was co-limiting at ~141us (R4: 49 waves/CU x 576 x 12cyc).
// Accumulators: 16 u32 (o-pair packed as two 16-bit halves, max 2304 < 2^16).
// Positions are m, m+256, m+512, m+768 -> per-o stores remain lane-contiguous.
// ---------------------------------------------------------------------------
__global__ __launch_bounds__(256, 4) void xnor_main_kernel(
    const uint32_t* __restrict__ xp, const uint32_t* __restrict__ wq,
    const float* __restrict__ sA, const float* __restrict__ sB,
    float* __restrict__ out)
{
    __shared__ uint32_t wlds[TAPS * OGRP * WWORDS];   // 576 words = 2304 B

    int obase = blockIdx.y * OGRP;
    int t = threadIdx.x;
    // Stage weights: 576 words, threads 0..191 write 3 each (contiguous).
    if (t < 192) {
        #pragma unroll
        for (int i = 0; i < 3; ++i) {
            int L = t * 3 + i;                 // 0..575
            int tap = L >> 6;                  // / (OGRP*WWORDS)
            int oo  = (L >> 3) & (OGRP - 1);
            int k   = L & 7;
            wlds[L] = wq[(((size_t)tap * OCH) + obase + oo) * WWORDS + k];
        }
    }
    __syncthreads();

    // 4 positions per thread: m, m+256, m+512, m+768 (grid.x*1024 = 100352 exact)
    const uint32_t* xbase[POSP];
    size_t oaddr[POSP];
    #pragma unroll
    for (int i = 0; i < POSP; ++i) {
        int m = blockIdx.x * 1024 + t + i * 256;
        int b = m / HWOUT;
        int r = m - b * HWOUT;
        int oy = r / WOUT;
        int ox = r - oy * WOUT;
        xbase[i] = xp + (((size_t)b * HIN + oy) * WIN2 + ox) * WWORDS;
        oaddr[i] = ((size_t)b * OCH + obase) * HWOUT + (size_t)oy * WOUT + ox;
    }

    uint32_t acc[(OGRP / 2) * POSP];          // [pair][pos]
    #pragma unroll
    for (int i = 0; i < (OGRP / 2) * POSP; ++i) acc[i] = 0u;

    #pragma unroll 1
    for (int tap = 0; tap < TAPS; ++tap) {
        int dy = tap / 3, dx = tap - dy * 3;           // wave-uniform -> SALU
        int toff = (dy * WIN2 + dx) * WWORDS;
        uint4 x0[POSP], x1[POSP];
        #pragma unroll
        for (int i = 0; i < POSP; ++i) {
            const uint4* s = (const uint4*)(xbase[i] + toff);
            x0[i] = s[0];
            x1[i] = s[1];
        }
        const uint4* wl = (const uint4*)&wlds[tap * OGRP * WWORDS];
        #pragma unroll
        for (int pp = 0; pp < OGRP / 2; ++pp) {
            uint4 wa = wl[pp * 4 + 0];                 // o_even words 0-3 (broadcast)
            uint4 wb2 = wl[pp * 4 + 1];                // o_even words 4-7
            uint4 wc = wl[pp * 4 + 2];                 // o_odd  words 0-3
            uint4 wd = wl[pp * 4 + 3];                 // o_odd  words 4-7
            #pragma unroll
            for (int i = 0; i < POSP; ++i) {
                uint32_t q0 = __popc(wa.x ^ x0[i].x);  // fused v_bcnt chains
                q0 += __popc(wa.y ^ x0[i].y);
                q0 += __popc(wa.z ^ x0[i].z);
                q0 += __popc(wa.w ^ x0[i].w);
                q0 += __popc(wb2.x ^ x1[i].x);
                q0 += __popc(wb2.y ^ x1[i].y);
                q0 += __popc(wb2.z ^ x1[i].z);
                q0 += __popc(wb2.w ^ x1[i].w);
                uint32_t q1 = __popc(wc.x ^ x0[i].x);
                q1 += __popc(wc.y ^ x0[i].y);
                q1 += __popc(wc.z ^ x0[i].z);
                q1 += __popc(wc.w ^ x0[i].w);
                q1 += __popc(wd.x ^ x1[i].x);
                q1 += __popc(wd.y ^ x1[i].y);
                q1 += __popc(wd.z ^ x1[i].z);
                q1 += __popc(wd.w ^ x1[i].w);
                acc[pp * POSP + i] += q0 + (q1 << 16); // lshl_add + add
            }
        }
    }

    #pragma unroll
    for (int pp = 0; pp < OGRP / 2; ++pp) {
        int o0 = obase + 2 * pp;
        float a0 = sA[o0], b0 = sB[o0];
        float a1 = sA[o0 + 1], b1 = sB[o0 + 1];
        #pragma unroll
        for (int i = 0; i < POSP; ++i) {
            uint32_t a = acc[pp * POSP + i];
            float P0 = (float)(a & 0xFFFFu);
            float P1 = (float)(a >> 16);
            out[oaddr[i] + (size_t)(2 * pp) * HWOUT]     = fmaf(a0, P0, b0);
            out[oaddr[i] + (size_t)(2 * pp + 1) * HWOUT] = fmaf(a1, P1, b1);
        }
    }
}

// ---------------------------------------------------------------------------
extern "C" void kernel_launch(void* const* d_in, const int* in_sizes, int n_in,
                              void* d_out, int out_size, void* d_ws, size_t ws_size,
                              hipStream_t stream)
{
    const float* x  = (const float*)d_in[0];
    const float* wt = (const float*)d_in[1];
    float* out = (float*)d_out;

    char* ws = (char*)d_ws;
    uint32_t* xp = (uint32_t*)ws;                               // 3,444,736 B
    uint32_t* wq = (uint32_t*)(ws + 3444736);                   //    73,728 B
    float*    sA = (float*)(ws + 3444736 + 73728);              //     1,024 B
    float*    sB = (float*)(ws + 3444736 + 73728 + 1024);       //     1,024 B

    // 1) pack x: 430,592 threads / 256 = 1682 blocks exactly
    pack_x_kernel<<<dim3(1682), dim3(256), 0, stream>>>(x, xp);

    // 2) pack weights (tap-major) + scales
    pack_w_kernel<<<dim3(OCH), dim3(256), 0, stream>>>(wt, wq, sA, sB);

    // 3) main: 98 position-blocks (1024 pos each) x 32 o-groups of 8
    xnor_main_kernel<<<dim3(98, 32), dim3(256), 0, stream>>>(xp, wq, sA, sB, out);
}